// Round 1
// baseline (1409.380 us; speedup 1.0000x reference)
//
#include <hip/hip_runtime.h>
#include <hip/hip_bf16.h>

// ---------- helpers ----------
__device__ __forceinline__ float4 f4fma(float s, float4 w, float4 a) {
    a.x = fmaf(s, w.x, a.x);
    a.y = fmaf(s, w.y, a.y);
    a.z = fmaf(s, w.z, a.z);
    a.w = fmaf(s, w.w, a.w);
    return a;
}

// ---------- branch 1x1 conv + BN + ReLU (a4: CIN=128, a32: CIN=256) ----------
template<int CIN>
__global__ __launch_bounds__(256) void k_branch(
    const float* __restrict__ x, const float* __restrict__ w,
    const float* __restrict__ s, const float* __restrict__ b,
    float* __restrict__ out, int npix) {
    int t = threadIdx.x;
    int f = t & 31;
    int pi = blockIdx.x * 8 + (t >> 5);
    if (pi >= npix) return;
    const float* xr = x + (size_t)pi * CIN;
    float acc = 0.f;
#pragma unroll 4
    for (int c = 0; c < CIN; ++c) acc = fmaf(xr[c], w[c * 32 + f], acc);
    float v = fmaf(acc, s[f], b[f]);
    out[(size_t)pi * 32 + f] = fmaxf(v, 0.f);
}

// ---------- cat builder: a2 (1x1 conv) + bilinear up of a4, a32 ----------
__global__ __launch_bounds__(256) void k_cat(
    const float* __restrict__ feats2, const float* __restrict__ w2,
    const float* __restrict__ s2, const float* __restrict__ b2,
    const float* __restrict__ a4, const float* __restrict__ a32,
    float* __restrict__ cat) {
    int t = threadIdx.x;
    int f = t & 31;
    int p = blockIdx.x * 8 + (t >> 5);   // 0..65535
    int y = p >> 8, x = p & 255;

    // a2: 64 -> 32 1x1 conv
    {
        const float* xr = feats2 + (size_t)p * 64;
        float acc = 0.f;
#pragma unroll 4
        for (int c = 0; c < 64; ++c) acc = fmaf(xr[c], w2[c * 32 + f], acc);
        float v = fmaf(acc, s2[f], b2[f]);
        cat[(size_t)p * 96 + f] = fmaxf(v, 0.f);
    }
    // a4: bilinear 128 -> 256 (half-pixel centers, edge-clamped == JAX renorm)
    {
        float sy = fminf(fmaxf(y * 0.5f - 0.25f, 0.f), 127.f);
        float sx = fminf(fmaxf(x * 0.5f - 0.25f, 0.f), 127.f);
        int y0 = (int)sy; float fy = sy - (float)y0; int y1 = min(y0 + 1, 127);
        int x0 = (int)sx; float fx = sx - (float)x0; int x1 = min(x0 + 1, 127);
        float v00 = a4[((size_t)(y0 * 128 + x0)) * 32 + f];
        float v01 = a4[((size_t)(y0 * 128 + x1)) * 32 + f];
        float v10 = a4[((size_t)(y1 * 128 + x0)) * 32 + f];
        float v11 = a4[((size_t)(y1 * 128 + x1)) * 32 + f];
        float vv = (1.f - fy) * ((1.f - fx) * v00 + fx * v01)
                 + fy * ((1.f - fx) * v10 + fx * v11);
        cat[(size_t)p * 96 + 32 + f] = vv;
    }
    // a32: bilinear 16 -> 256
    {
        float sy = fminf(fmaxf((y + 0.5f) * (1.f / 16.f) - 0.5f, 0.f), 15.f);
        float sx = fminf(fmaxf((x + 0.5f) * (1.f / 16.f) - 0.5f, 0.f), 15.f);
        int y0 = (int)sy; float fy = sy - (float)y0; int y1 = min(y0 + 1, 15);
        int x0 = (int)sx; float fx = sx - (float)x0; int x1 = min(x0 + 1, 15);
        float v00 = a32[((size_t)(y0 * 16 + x0)) * 32 + f];
        float v01 = a32[((size_t)(y0 * 16 + x1)) * 32 + f];
        float v10 = a32[((size_t)(y1 * 16 + x0)) * 32 + f];
        float v11 = a32[((size_t)(y1 * 16 + x1)) * 32 + f];
        float vv = (1.f - fy) * ((1.f - fx) * v00 + fx * v01)
                 + fy * ((1.f - fx) * v10 + fx * v11);
        cat[(size_t)p * 96 + 64 + f] = vv;
    }
}

// ---------- 3x3 conv (SAME, zero pad) + BN + ReLU : 96 -> 96 ----------
// grid: (1024 tiles of 8x8 px, 3 fo-groups of 32). block 256.
// wave w handles 64 px x 8 fo; LDS holds 10x10x96 input tile, ch-major.
__global__ __launch_bounds__(256) void k_fuse(
    const float* __restrict__ cat, const float* __restrict__ wf,
    const float* __restrict__ sf, const float* __restrict__ bf,
    float* __restrict__ out) {
    __shared__ float lds[96 * 100];   // [ci][yy*10+xx], pitch 100
    int t = threadIdx.x;
    int tile = blockIdx.x;
    int by = (tile >> 5) * 8, bx = (tile & 31) * 8;

    for (int i = t; i < 9600; i += 256) {
        int ci = i % 96;
        int pix = i / 96;
        int yy = pix / 10, xx = pix % 10;
        int gy = by + yy - 1, gx = bx + xx - 1;
        float v = 0.f;
        if (gy >= 0 && gy < 256 && gx >= 0 && gx < 256)
            v = cat[((size_t)(gy * 256 + gx)) * 96 + ci];
        lds[ci * 100 + yy * 10 + xx] = v;
    }
    __syncthreads();

    int lane = t & 63;
    int xx = lane & 7, yy = lane >> 3;
    int fo = blockIdx.y * 32 + (t >> 6) * 8;

    float acc[8] = {0.f, 0.f, 0.f, 0.f, 0.f, 0.f, 0.f, 0.f};
#pragma unroll
    for (int ky = 0; ky < 3; ++ky) {
#pragma unroll
        for (int kx = 0; kx < 3; ++kx) {
            const float* wbase = wf + ((size_t)((ky * 3 + kx) * 96)) * 96 + fo;
            const float* lbase = lds + (yy + ky) * 10 + (xx + kx);
#pragma unroll 4
            for (int ci = 0; ci < 96; ++ci) {
                float v = lbase[ci * 100];
                float4 wa = *(const float4*)(wbase + ci * 96);
                float4 wb = *(const float4*)(wbase + ci * 96 + 4);
                acc[0] = fmaf(v, wa.x, acc[0]);
                acc[1] = fmaf(v, wa.y, acc[1]);
                acc[2] = fmaf(v, wa.z, acc[2]);
                acc[3] = fmaf(v, wa.w, acc[3]);
                acc[4] = fmaf(v, wb.x, acc[4]);
                acc[5] = fmaf(v, wb.y, acc[5]);
                acc[6] = fmaf(v, wb.z, acc[6]);
                acc[7] = fmaf(v, wb.w, acc[7]);
            }
        }
    }
    int p = (by + yy) * 256 + (bx + xx);
#pragma unroll
    for (int j = 0; j < 8; ++j) {
        float vv = fmaf(acc[j], sf[fo + j], bf[fo + j]);
        out[(size_t)p * 96 + fo + j] = fmaxf(vv, 0.f);
    }
}

// ---------- fused LIIF query + MLP + ensemble ----------
// block 256, 16 query px = 64 MLP rows. layer0/1 register tiled 8x4, layer2 fused.
__global__ __launch_bounds__(256) void k_mlp(
    const float* __restrict__ feat,
    const float* __restrict__ w0g, const float* __restrict__ b0g,
    const float* __restrict__ w1g, const float* __restrict__ b1g,
    const float* __restrict__ w2g, const float* __restrict__ b2g,
    float* __restrict__ out) {
    __shared__ float xb[64][100];
    __shared__ float h0[64][128];
    __shared__ float areas[64];
    __shared__ float preds[64];
    int t = threadIdx.x;

    // phase 0: gather MLP inputs (4 branches per query pixel)
    {
        int row = t >> 2, j = t & 3;
        int p = blockIdx.x * 16 + (row >> 2);
        int br = row & 3;                 // (vx,vy): 0:(-,-) 1:(-,+) 2:(+,-) 3:(+,+)
        int qy = p >> 9, qx = p & 511;
        float vx = (br & 2) ? 1.f : -1.f;
        float vy = (br & 1) ? 1.f : -1.f;
        float gy = (qy + 0.5f) * (1.f / 256.f) - 1.f;   // == make_coords(512)
        float gx = (qx + 0.5f) * (1.f / 256.f) - 1.f;
        float csy = fminf(fmaxf(gy + (vx * (1.f / 256.f) + 1e-6f), -1.f + 1e-6f), 1.f - 1e-6f);
        float csx = fminf(fmaxf(gx + (vy * (1.f / 256.f) + 1e-6f), -1.f + 1e-6f), 1.f - 1e-6f);
        int iy = min(max((int)rintf((csy + 1.f) * 128.f - 0.5f), 0), 255);
        int ix = min(max((int)rintf((csx + 1.f) * 128.f - 0.5f), 0), 255);
        float qcy = (iy + 0.5f) * (1.f / 128.f) - 1.f;
        float qcx = (ix + 0.5f) * (1.f / 128.f) - 1.f;
        float ry = (gy - qcy) * 256.f;
        float rx = (gx - qcx) * 256.f;
        const float4* src = (const float4*)(feat + ((size_t)(iy * 256 + ix)) * 96 + j * 24);
        float4* dst = (float4*)(&xb[row][j * 24]);
#pragma unroll
        for (int m = 0; m < 6; ++m) dst[m] = src[m];
        if (j == 0) {
            xb[row][96] = ry;
            xb[row][97] = rx;
            areas[row] = fabsf(ry * rx) + 1e-9f;
        }
    }
    __syncthreads();

    int tx = t & 31, ty = t >> 5;
    // ----- layer 0: 98 -> 128, relu -----
    {
        float4 acc[8];
#pragma unroll
        for (int r = 0; r < 8; ++r) acc[r] = make_float4(0.f, 0.f, 0.f, 0.f);
        for (int k = 0; k < 96; k += 4) {
            float4 wv0 = *(const float4*)(w0g + (size_t)(k + 0) * 128 + tx * 4);
            float4 wv1 = *(const float4*)(w0g + (size_t)(k + 1) * 128 + tx * 4);
            float4 wv2 = *(const float4*)(w0g + (size_t)(k + 2) * 128 + tx * 4);
            float4 wv3 = *(const float4*)(w0g + (size_t)(k + 3) * 128 + tx * 4);
#pragma unroll
            for (int r = 0; r < 8; ++r) {
                float4 xv = *(const float4*)(&xb[ty * 8 + r][k]);
                acc[r] = f4fma(xv.x, wv0, acc[r]);
                acc[r] = f4fma(xv.y, wv1, acc[r]);
                acc[r] = f4fma(xv.z, wv2, acc[r]);
                acc[r] = f4fma(xv.w, wv3, acc[r]);
            }
        }
        float4 wA = *(const float4*)(w0g + (size_t)96 * 128 + tx * 4);
        float4 wB = *(const float4*)(w0g + (size_t)97 * 128 + tx * 4);
        float4 bias = *(const float4*)(b0g + tx * 4);
#pragma unroll
        for (int r = 0; r < 8; ++r) {
            acc[r] = f4fma(xb[ty * 8 + r][96], wA, acc[r]);
            acc[r] = f4fma(xb[ty * 8 + r][97], wB, acc[r]);
            float4 h;
            h.x = fmaxf(acc[r].x + bias.x, 0.f);
            h.y = fmaxf(acc[r].y + bias.y, 0.f);
            h.z = fmaxf(acc[r].z + bias.z, 0.f);
            h.w = fmaxf(acc[r].w + bias.w, 0.f);
            *(float4*)(&h0[ty * 8 + r][tx * 4]) = h;
        }
    }
    __syncthreads();

    // ----- layer 1: 128 -> 128, relu; fused layer 2: 128 -> 1 -----
    {
        float4 acc[8];
#pragma unroll
        for (int r = 0; r < 8; ++r) acc[r] = make_float4(0.f, 0.f, 0.f, 0.f);
        for (int k = 0; k < 128; k += 4) {
            float4 wv0 = *(const float4*)(w1g + (size_t)(k + 0) * 128 + tx * 4);
            float4 wv1 = *(const float4*)(w1g + (size_t)(k + 1) * 128 + tx * 4);
            float4 wv2 = *(const float4*)(w1g + (size_t)(k + 2) * 128 + tx * 4);
            float4 wv3 = *(const float4*)(w1g + (size_t)(k + 3) * 128 + tx * 4);
#pragma unroll
            for (int r = 0; r < 8; ++r) {
                float4 hv = *(const float4*)(&h0[ty * 8 + r][k]);
                acc[r] = f4fma(hv.x, wv0, acc[r]);
                acc[r] = f4fma(hv.y, wv1, acc[r]);
                acc[r] = f4fma(hv.z, wv2, acc[r]);
                acc[r] = f4fma(hv.w, wv3, acc[r]);
            }
        }
        float4 b1v = *(const float4*)(b1g + tx * 4);
        float4 w2v = *(const float4*)(w2g + tx * 4);
        float part[8];
#pragma unroll
        for (int r = 0; r < 8; ++r) {
            float hx = fmaxf(acc[r].x + b1v.x, 0.f);
            float hy = fmaxf(acc[r].y + b1v.y, 0.f);
            float hz = fmaxf(acc[r].z + b1v.z, 0.f);
            float hw = fmaxf(acc[r].w + b1v.w, 0.f);
            part[r] = hx * w2v.x + hy * w2v.y + hz * w2v.z + hw * w2v.w;
        }
#pragma unroll
        for (int off = 16; off >= 1; off >>= 1) {
#pragma unroll
            for (int r = 0; r < 8; ++r) part[r] += __shfl_xor(part[r], off);
        }
        if (tx == 0) {
            float bb = b2g[0];
#pragma unroll
            for (int r = 0; r < 8; ++r) preds[ty * 8 + r] = part[r] + bb;
        }
    }
    __syncthreads();

    // ----- local ensemble (swapped diagonal areas) -----
    if (t < 16) {
        int p = blockIdx.x * 16 + t;
        float p0 = preds[t * 4 + 0], p1 = preds[t * 4 + 1];
        float p2 = preds[t * 4 + 2], p3 = preds[t * 4 + 3];
        float a0 = areas[t * 4 + 0], A1 = areas[t * 4 + 1];
        float A2 = areas[t * 4 + 2], A3 = areas[t * 4 + 3];
        out[p] = (p0 * A3 + p1 * A2 + p2 * A1 + p3 * a0) / (a0 + A1 + A2 + A3);
    }
}

// ---------- host launcher ----------
extern "C" void kernel_launch(void* const* d_in, const int* in_sizes, int n_in,
                              void* d_out, int out_size, void* d_ws, size_t ws_size,
                              hipStream_t stream) {
    const float* feats2 = (const float*)d_in[0];   // 1,256,256,64
    const float* feats4 = (const float*)d_in[1];   // 1,128,128,128
    const float* feats32 = (const float*)d_in[2];  // 1,16,16,256
    // d_in[3] coords: recomputed exactly in-kernel
    const float* w2 = (const float*)d_in[4];
    const float* s2 = (const float*)d_in[5];
    const float* b2 = (const float*)d_in[6];
    const float* w4 = (const float*)d_in[7];
    const float* s4 = (const float*)d_in[8];
    const float* b4 = (const float*)d_in[9];
    const float* w32 = (const float*)d_in[10];
    const float* s32 = (const float*)d_in[11];
    const float* b32 = (const float*)d_in[12];
    const float* wf = (const float*)d_in[13];
    const float* sf = (const float*)d_in[14];
    const float* bf = (const float*)d_in[15];
    const float* mw0 = (const float*)d_in[16];
    const float* mb0 = (const float*)d_in[17];
    const float* mw1 = (const float*)d_in[18];
    const float* mb1 = (const float*)d_in[19];
    const float* mw2 = (const float*)d_in[20];
    const float* mb2 = (const float*)d_in[21];

    float* a4buf = (float*)d_ws;                 // 128*128*32
    float* a32buf = a4buf + 524288;              // 16*16*32
    float* catbuf = a32buf + 8192;               // 256*256*96
    float* featbuf = catbuf + 6291456;           // 256*256*96

    k_branch<128><<<2048, 256, 0, stream>>>(feats4, w4, s4, b4, a4buf, 16384);
    k_branch<256><<<32, 256, 0, stream>>>(feats32, w32, s32, b32, a32buf, 256);
    k_cat<<<8192, 256, 0, stream>>>(feats2, w2, s2, b2, a4buf, a32buf, catbuf);
    k_fuse<<<dim3(1024, 3), 256, 0, stream>>>(catbuf, wf, sf, bf, featbuf);
    k_mlp<<<16384, 256, 0, stream>>>(featbuf, mw0, mb0, mw1, mb1, mw2, mb2,
                                     (float*)d_out);
}

// Round 2
// 449.668 us; speedup vs baseline: 3.1343x; 3.1343x over previous
//
#include <hip/hip_runtime.h>
#include <hip/hip_bf16.h>

typedef __attribute__((ext_vector_type(8))) short short8v;
typedef __attribute__((ext_vector_type(4))) float float4v;

__device__ __forceinline__ unsigned short f2bf(float x) {
    unsigned u = __float_as_uint(x);
    unsigned r = (u + 0x7fffu + ((u >> 16) & 1u)) >> 16;
    return (unsigned short)r;
}

__device__ __forceinline__ float4 f4fma(float s, float4 w, float4 a) {
    a.x = fmaf(s, w.x, a.x);
    a.y = fmaf(s, w.y, a.y);
    a.z = fmaf(s, w.z, a.z);
    a.w = fmaf(s, w.w, a.w);
    return a;
}

// ---------- branch 1x1 conv + BN + ReLU (a4: CIN=128, a32: CIN=256) ----------
template<int CIN>
__global__ __launch_bounds__(256) void k_branch(
    const float* __restrict__ x, const float* __restrict__ w,
    const float* __restrict__ s, const float* __restrict__ b,
    float* __restrict__ out, int npix) {
    int t = threadIdx.x;
    int f = t & 31;
    int pi = blockIdx.x * 8 + (t >> 5);
    if (pi >= npix) return;
    const float* xr = x + (size_t)pi * CIN;
    float acc = 0.f;
#pragma unroll 4
    for (int c = 0; c < CIN; ++c) acc = fmaf(xr[c], w[c * 32 + f], acc);
    float v = fmaf(acc, s[f], b[f]);
    out[(size_t)pi * 32 + f] = fmaxf(v, 0.f);
}

// ---------- cat builder: a2 (1x1 conv) + bilinear up of a4, a32 ----------
__global__ __launch_bounds__(256) void k_cat(
    const float* __restrict__ feats2, const float* __restrict__ w2,
    const float* __restrict__ s2, const float* __restrict__ b2,
    const float* __restrict__ a4, const float* __restrict__ a32,
    float* __restrict__ cat) {
    int t = threadIdx.x;
    int f = t & 31;
    int p = blockIdx.x * 8 + (t >> 5);   // 0..65535
    int y = p >> 8, x = p & 255;

    {
        const float* xr = feats2 + (size_t)p * 64;
        float acc = 0.f;
#pragma unroll 4
        for (int c = 0; c < 64; ++c) acc = fmaf(xr[c], w2[c * 32 + f], acc);
        float v = fmaf(acc, s2[f], b2[f]);
        cat[(size_t)p * 96 + f] = fmaxf(v, 0.f);
    }
    {
        float sy = fminf(fmaxf(y * 0.5f - 0.25f, 0.f), 127.f);
        float sx = fminf(fmaxf(x * 0.5f - 0.25f, 0.f), 127.f);
        int y0 = (int)sy; float fy = sy - (float)y0; int y1 = min(y0 + 1, 127);
        int x0 = (int)sx; float fx = sx - (float)x0; int x1 = min(x0 + 1, 127);
        float v00 = a4[((size_t)(y0 * 128 + x0)) * 32 + f];
        float v01 = a4[((size_t)(y0 * 128 + x1)) * 32 + f];
        float v10 = a4[((size_t)(y1 * 128 + x0)) * 32 + f];
        float v11 = a4[((size_t)(y1 * 128 + x1)) * 32 + f];
        float vv = (1.f - fy) * ((1.f - fx) * v00 + fx * v01)
                 + fy * ((1.f - fx) * v10 + fx * v11);
        cat[(size_t)p * 96 + 32 + f] = vv;
    }
    {
        float sy = fminf(fmaxf((y + 0.5f) * (1.f / 16.f) - 0.5f, 0.f), 15.f);
        float sx = fminf(fmaxf((x + 0.5f) * (1.f / 16.f) - 0.5f, 0.f), 15.f);
        int y0 = (int)sy; float fy = sy - (float)y0; int y1 = min(y0 + 1, 15);
        int x0 = (int)sx; float fx = sx - (float)x0; int x1 = min(x0 + 1, 15);
        float v00 = a32[((size_t)(y0 * 16 + x0)) * 32 + f];
        float v01 = a32[((size_t)(y0 * 16 + x1)) * 32 + f];
        float v10 = a32[((size_t)(y1 * 16 + x0)) * 32 + f];
        float v11 = a32[((size_t)(y1 * 16 + x1)) * 32 + f];
        float vv = (1.f - fy) * ((1.f - fx) * v00 + fx * v01)
                 + fy * ((1.f - fx) * v10 + fx * v11);
        cat[(size_t)p * 96 + 64 + f] = vv;
    }
}

// ---------- 3x3 conv (SAME, zero pad) + BN + ReLU : 96 -> 96 ----------
__global__ __launch_bounds__(256) void k_fuse(
    const float* __restrict__ cat, const float* __restrict__ wf,
    const float* __restrict__ sf, const float* __restrict__ bf,
    float* __restrict__ out) {
    __shared__ float lds[96 * 100];   // [ci][yy*10+xx], pitch 100
    int t = threadIdx.x;
    int tile = blockIdx.x;
    int by = (tile >> 5) * 8, bx = (tile & 31) * 8;

    for (int i = t; i < 9600; i += 256) {
        int ci = i % 96;
        int pix = i / 96;
        int yy = pix / 10, xx = pix % 10;
        int gy = by + yy - 1, gx = bx + xx - 1;
        float v = 0.f;
        if (gy >= 0 && gy < 256 && gx >= 0 && gx < 256)
            v = cat[((size_t)(gy * 256 + gx)) * 96 + ci];
        lds[ci * 100 + yy * 10 + xx] = v;
    }
    __syncthreads();

    int lane = t & 63;
    int xx = lane & 7, yy = lane >> 3;
    // wave-uniform fo, forced to SGPR so weight loads can scalarize
    int fo = __builtin_amdgcn_readfirstlane(blockIdx.y * 32 + (t >> 6) * 8);

    float acc[8] = {0.f, 0.f, 0.f, 0.f, 0.f, 0.f, 0.f, 0.f};
#pragma unroll
    for (int ky = 0; ky < 3; ++ky) {
#pragma unroll
        for (int kx = 0; kx < 3; ++kx) {
            const float* wbase = wf + ((size_t)((ky * 3 + kx) * 96)) * 96 + fo;
            const float* lbase = lds + (yy + ky) * 10 + (xx + kx);
#pragma unroll 4
            for (int ci = 0; ci < 96; ++ci) {
                float v = lbase[ci * 100];
                float4 wa = *(const float4*)(wbase + ci * 96);
                float4 wb = *(const float4*)(wbase + ci * 96 + 4);
                acc[0] = fmaf(v, wa.x, acc[0]);
                acc[1] = fmaf(v, wa.y, acc[1]);
                acc[2] = fmaf(v, wa.z, acc[2]);
                acc[3] = fmaf(v, wa.w, acc[3]);
                acc[4] = fmaf(v, wb.x, acc[4]);
                acc[5] = fmaf(v, wb.y, acc[5]);
                acc[6] = fmaf(v, wb.z, acc[6]);
                acc[7] = fmaf(v, wb.w, acc[7]);
            }
        }
    }
    int p = (by + yy) * 256 + (bx + xx);
#pragma unroll
    for (int j = 0; j < 8; ++j) {
        float vv = fmaf(acc[j], sf[fo + j], bf[fo + j]);
        out[(size_t)p * 96 + fo + j] = fmaxf(vv, 0.f);
    }
}

// ---------- pack MLP weights into MFMA B-fragment order (bf16) ----------
// layout: elem[((kt*8+nt)*64 + lane)*8 + j] = W[k][n], k=kt*32+(lane>>4)*8+j, n=nt*16+(lane&15)
__global__ __launch_bounds__(256) void k_pack(
    const float* __restrict__ w0, const float* __restrict__ w1,
    short* __restrict__ w0p, short* __restrict__ w1p) {
    int i = blockIdx.x * 256 + threadIdx.x;   // 0..16383
    int j = i & 7;
    int l = (i >> 3) & 63;
    int nt = (i >> 9) & 7;
    int kt = i >> 12;
    int k = kt * 32 + ((l >> 4) << 3) + j;
    int n = nt * 16 + (l & 15);
    w0p[i] = (k < 98) ? (short)f2bf(w0[k * 128 + n]) : (short)0;
    w1p[i] = (short)f2bf(w1[k * 128 + n]);
}

// ---------- fused LIIF query + MLP (bf16 MFMA) + ensemble ----------
// block 256 = 4 waves; 128 MLP rows = 32 query px. X/H share a 32KB swizzled LDS tile.
__global__ __launch_bounds__(256) void k_mlp2(
    const float* __restrict__ feat,
    const short* __restrict__ w0p, const float* __restrict__ b0g,
    const short* __restrict__ w1p, const float* __restrict__ b1g,
    const float* __restrict__ w2g, const float* __restrict__ b2g,
    float* __restrict__ out) {
    __shared__ short8v Xs[128 * 128 / 8];   // 32KB bf16 [row][k], XOR-swizzled
    __shared__ float areas[128];
    __shared__ float preds[128];
    char* Xb = (char*)Xs;
    int t = threadIdx.x;

    // ---- phase 0: gather X = [feat(96) | ry rx | 0-pad] as bf16 ----
    {
        int row = t >> 1, hf = t & 1;
        int pixl = row >> 2, br = row & 3;    // br: 0:(-,-) 1:(-,+) 2:(+,-) 3:(+,+)
        int p = blockIdx.x * 32 + pixl;
        int qy = p >> 9, qx = p & 511;
        float vx = (br & 2) ? 1.f : -1.f;
        float vy = (br & 1) ? 1.f : -1.f;
        float gy = (qy + 0.5f) * (1.f / 256.f) - 1.f;
        float gx = (qx + 0.5f) * (1.f / 256.f) - 1.f;
        float csy = fminf(fmaxf(gy + (vx * (1.f / 256.f) + 1e-6f), -1.f + 1e-6f), 1.f - 1e-6f);
        float csx = fminf(fmaxf(gx + (vy * (1.f / 256.f) + 1e-6f), -1.f + 1e-6f), 1.f - 1e-6f);
        int iy = min(max((int)rintf((csy + 1.f) * 128.f - 0.5f), 0), 255);
        int ix = min(max((int)rintf((csx + 1.f) * 128.f - 0.5f), 0), 255);
        float qcy = (iy + 0.5f) * (1.f / 128.f) - 1.f;
        float qcx = (ix + 0.5f) * (1.f / 128.f) - 1.f;
        float ry = (gy - qcy) * 256.f;
        float rx = (gx - qcx) * 256.f;
        const float* fp = feat + ((size_t)(iy * 256 + ix)) * 96;
        int rswz = (row & 7) << 4;
#pragma unroll
        for (int cc = 0; cc < 8; ++cc) {
            int ch = hf * 8 + cc;
            short8v v;
            if (ch < 12) {
                float4 xa = *(const float4*)(fp + ch * 8);
                float4 xc = *(const float4*)(fp + ch * 8 + 4);
                v[0] = (short)f2bf(xa.x); v[1] = (short)f2bf(xa.y);
                v[2] = (short)f2bf(xa.z); v[3] = (short)f2bf(xa.w);
                v[4] = (short)f2bf(xc.x); v[5] = (short)f2bf(xc.y);
                v[6] = (short)f2bf(xc.z); v[7] = (short)f2bf(xc.w);
            } else if (ch == 12) {
                v[0] = (short)f2bf(ry); v[1] = (short)f2bf(rx);
                v[2] = 0; v[3] = 0; v[4] = 0; v[5] = 0; v[6] = 0; v[7] = 0;
            } else {
                v[0] = 0; v[1] = 0; v[2] = 0; v[3] = 0;
                v[4] = 0; v[5] = 0; v[6] = 0; v[7] = 0;
            }
            int byteoff = row * 256 + ((ch * 16) ^ rswz);
            *(short8v*)(Xb + byteoff) = v;
        }
        if (hf == 0) areas[row] = fabsf(ry * rx) + 1e-9f;
    }
    __syncthreads();

    int lane = t & 63, wid = t >> 6;
    int arow0 = wid * 32 + (lane & 15);
    int arow1 = arow0 + 16;
    int kb = (lane >> 4) * 16;           // byte offset of this lane's k-slice
    int rs0 = (arow0 & 7) << 4;          // same for arow1 (differs by 16)
    int col = lane & 15;
    int rbase = (lane >> 4) * 4;

    float4v acc[2][8];
#pragma unroll
    for (int rt = 0; rt < 2; ++rt)
#pragma unroll
        for (int nt = 0; nt < 8; ++nt)
            acc[rt][nt] = (float4v){0.f, 0.f, 0.f, 0.f};

    // ---- layer 0: X[128x128bf16] @ W0p -> H ----
#pragma unroll
    for (int kt = 0; kt < 4; ++kt) {
        short8v a0 = *(short8v*)(Xb + arow0 * 256 + ((kt * 64 + kb) ^ rs0));
        short8v a1 = *(short8v*)(Xb + arow1 * 256 + ((kt * 64 + kb) ^ rs0));
        const short8v* bp = (const short8v*)w0p + kt * 512 + lane;
#pragma unroll
        for (int nt = 0; nt < 8; ++nt) {
            short8v b = bp[nt * 64];
            acc[0][nt] = __builtin_amdgcn_mfma_f32_16x16x32_bf16(a0, b, acc[0][nt], 0, 0, 0);
            acc[1][nt] = __builtin_amdgcn_mfma_f32_16x16x32_bf16(a1, b, acc[1][nt], 0, 0, 0);
        }
    }
    __syncthreads();   // all X reads done before overwrite

    // bias + relu, write H (bf16) into same LDS
#pragma unroll
    for (int rt = 0; rt < 2; ++rt) {
#pragma unroll
        for (int nt = 0; nt < 8; ++nt) {
            float b0v = b0g[nt * 16 + col];
#pragma unroll
            for (int j = 0; j < 4; ++j) {
                int rr = wid * 32 + rt * 16 + rbase + j;
                float h = fmaxf(acc[rt][nt][j] + b0v, 0.f);
                int byteoff = rr * 256 + (((nt * 32 + col * 2)) ^ ((rr & 7) << 4));
                *(short*)(Xb + byteoff) = (short)f2bf(h);
            }
        }
    }
    __syncthreads();

#pragma unroll
    for (int rt = 0; rt < 2; ++rt)
#pragma unroll
        for (int nt = 0; nt < 8; ++nt)
            acc[rt][nt] = (float4v){0.f, 0.f, 0.f, 0.f};

    // ---- layer 1: H @ W1p ----
#pragma unroll
    for (int kt = 0; kt < 4; ++kt) {
        short8v a0 = *(short8v*)(Xb + arow0 * 256 + ((kt * 64 + kb) ^ rs0));
        short8v a1 = *(short8v*)(Xb + arow1 * 256 + ((kt * 64 + kb) ^ rs0));
        const short8v* bp = (const short8v*)w1p + kt * 512 + lane;
#pragma unroll
        for (int nt = 0; nt < 8; ++nt) {
            short8v b = bp[nt * 64];
            acc[0][nt] = __builtin_amdgcn_mfma_f32_16x16x32_bf16(a0, b, acc[0][nt], 0, 0, 0);
            acc[1][nt] = __builtin_amdgcn_mfma_f32_16x16x32_bf16(a1, b, acc[1][nt], 0, 0, 0);
        }
    }

    // ---- fused layer 2 + reduction ----
    float b1v[8], w2v[8];
#pragma unroll
    for (int nt = 0; nt < 8; ++nt) {
        b1v[nt] = b1g[nt * 16 + col];
        w2v[nt] = w2g[nt * 16 + col];
    }
    float part[2][4];
#pragma unroll
    for (int rt = 0; rt < 2; ++rt)
#pragma unroll
        for (int j = 0; j < 4; ++j) part[rt][j] = 0.f;
#pragma unroll
    for (int rt = 0; rt < 2; ++rt)
#pragma unroll
        for (int nt = 0; nt < 8; ++nt)
#pragma unroll
            for (int j = 0; j < 4; ++j)
                part[rt][j] += fmaxf(acc[rt][nt][j] + b1v[nt], 0.f) * w2v[nt];
#pragma unroll
    for (int off = 8; off >= 1; off >>= 1)
#pragma unroll
        for (int rt = 0; rt < 2; ++rt)
#pragma unroll
            for (int j = 0; j < 4; ++j)
                part[rt][j] += __shfl_xor(part[rt][j], off);
    if ((lane & 15) == 0) {
        float bb = b2g[0];
#pragma unroll
        for (int rt = 0; rt < 2; ++rt)
#pragma unroll
            for (int j = 0; j < 4; ++j)
                preds[wid * 32 + rt * 16 + rbase + j] = part[rt][j] + bb;
    }
    __syncthreads();

    // ---- local ensemble (swapped diagonal areas) ----
    if (t < 32) {
        int p = blockIdx.x * 32 + t;
        float p0 = preds[t * 4 + 0], p1 = preds[t * 4 + 1];
        float p2 = preds[t * 4 + 2], p3 = preds[t * 4 + 3];
        float a0 = areas[t * 4 + 0], A1 = areas[t * 4 + 1];
        float A2 = areas[t * 4 + 2], A3 = areas[t * 4 + 3];
        out[p] = (p0 * A3 + p1 * A2 + p2 * A1 + p3 * a0) / (a0 + A1 + A2 + A3);
    }
}

// ---------- host launcher ----------
extern "C" void kernel_launch(void* const* d_in, const int* in_sizes, int n_in,
                              void* d_out, int out_size, void* d_ws, size_t ws_size,
                              hipStream_t stream) {
    const float* feats2 = (const float*)d_in[0];
    const float* feats4 = (const float*)d_in[1];
    const float* feats32 = (const float*)d_in[2];
    const float* w2 = (const float*)d_in[4];
    const float* s2 = (const float*)d_in[5];
    const float* b2 = (const float*)d_in[6];
    const float* w4 = (const float*)d_in[7];
    const float* s4 = (const float*)d_in[8];
    const float* b4 = (const float*)d_in[9];
    const float* w32 = (const float*)d_in[10];
    const float* s32 = (const float*)d_in[11];
    const float* b32 = (const float*)d_in[12];
    const float* wf = (const float*)d_in[13];
    const float* sf = (const float*)d_in[14];
    const float* bf = (const float*)d_in[15];
    const float* mw0 = (const float*)d_in[16];
    const float* mb0 = (const float*)d_in[17];
    const float* mw1 = (const float*)d_in[18];
    const float* mb1 = (const float*)d_in[19];
    const float* mw2 = (const float*)d_in[20];
    const float* mb2 = (const float*)d_in[21];

    float* a4buf = (float*)d_ws;                 // 128*128*32
    float* a32buf = a4buf + 524288;              // 16*16*32
    float* catbuf = a32buf + 8192;               // 256*256*96
    float* featbuf = catbuf + 6291456;           // 256*256*96
    short* w0p = (short*)(featbuf + 6291456);    // 4*8*64*8 bf16
    short* w1p = w0p + 16384;

    k_pack<<<64, 256, 0, stream>>>(mw0, mw1, w0p, w1p);
    k_branch<128><<<2048, 256, 0, stream>>>(feats4, w4, s4, b4, a4buf, 16384);
    k_branch<256><<<32, 256, 0, stream>>>(feats32, w32, s32, b32, a32buf, 256);
    k_cat<<<8192, 256, 0, stream>>>(feats2, w2, s2, b2, a4buf, a32buf, catbuf);
    k_fuse<<<dim3(1024, 3), 256, 0, stream>>>(catbuf, wf, sf, bf, featbuf);
    k_mlp2<<<8192, 256, 0, stream>>>(featbuf, w0p, mb0, w1p, mb1, mw2, mb2,
                                     (float*)d_out);
}

// Round 3
// 255.686 us; speedup vs baseline: 5.5122x; 1.7587x over previous
//
#include <hip/hip_runtime.h>
#include <hip/hip_bf16.h>

typedef __attribute__((ext_vector_type(8))) short short8v;
typedef __attribute__((ext_vector_type(4))) float float4v;

__device__ __forceinline__ unsigned short f2bf(float x) {
    unsigned u = __float_as_uint(x);
    unsigned r = (u + 0x7fffu + ((u >> 16) & 1u)) >> 16;
    return (unsigned short)r;
}

// ---------- branch 1x1 conv + BN + ReLU (a4: CIN=128, a32: CIN=256) ----------
template<int CIN>
__global__ __launch_bounds__(256) void k_branch(
    const float* __restrict__ x, const float* __restrict__ w,
    const float* __restrict__ s, const float* __restrict__ b,
    float* __restrict__ out, int npix) {
    int t = threadIdx.x;
    int f = t & 31;
    int pi = blockIdx.x * 8 + (t >> 5);
    if (pi >= npix) return;
    const float* xr = x + (size_t)pi * CIN;
    float acc = 0.f;
#pragma unroll 4
    for (int c = 0; c < CIN; ++c) acc = fmaf(xr[c], w[c * 32 + f], acc);
    float v = fmaf(acc, s[f], b[f]);
    out[(size_t)pi * 32 + f] = fmaxf(v, 0.f);
}

// ---------- cat builder: a2 (1x1 conv) + bilinear up of a4, a32 -> bf16 ----------
__global__ __launch_bounds__(256) void k_cat(
    const float* __restrict__ feats2, const float* __restrict__ w2,
    const float* __restrict__ s2, const float* __restrict__ b2,
    const float* __restrict__ a4, const float* __restrict__ a32,
    unsigned short* __restrict__ cat) {
    int t = threadIdx.x;
    int f = t & 31;
    int p = blockIdx.x * 8 + (t >> 5);   // 0..65535
    int y = p >> 8, x = p & 255;

    {
        const float* xr = feats2 + (size_t)p * 64;
        float acc = 0.f;
#pragma unroll 4
        for (int c = 0; c < 64; ++c) acc = fmaf(xr[c], w2[c * 32 + f], acc);
        float v = fmaf(acc, s2[f], b2[f]);
        cat[(size_t)p * 96 + f] = f2bf(fmaxf(v, 0.f));
    }
    {
        float sy = fminf(fmaxf(y * 0.5f - 0.25f, 0.f), 127.f);
        float sx = fminf(fmaxf(x * 0.5f - 0.25f, 0.f), 127.f);
        int y0 = (int)sy; float fy = sy - (float)y0; int y1 = min(y0 + 1, 127);
        int x0 = (int)sx; float fx = sx - (float)x0; int x1 = min(x0 + 1, 127);
        float v00 = a4[((size_t)(y0 * 128 + x0)) * 32 + f];
        float v01 = a4[((size_t)(y0 * 128 + x1)) * 32 + f];
        float v10 = a4[((size_t)(y1 * 128 + x0)) * 32 + f];
        float v11 = a4[((size_t)(y1 * 128 + x1)) * 32 + f];
        float vv = (1.f - fy) * ((1.f - fx) * v00 + fx * v01)
                 + fy * ((1.f - fx) * v10 + fx * v11);
        cat[(size_t)p * 96 + 32 + f] = f2bf(vv);
    }
    {
        float sy = fminf(fmaxf((y + 0.5f) * (1.f / 16.f) - 0.5f, 0.f), 15.f);
        float sx = fminf(fmaxf((x + 0.5f) * (1.f / 16.f) - 0.5f, 0.f), 15.f);
        int y0 = (int)sy; float fy = sy - (float)y0; int y1 = min(y0 + 1, 15);
        int x0 = (int)sx; float fx = sx - (float)x0; int x1 = min(x0 + 1, 15);
        float v00 = a32[((size_t)(y0 * 16 + x0)) * 32 + f];
        float v01 = a32[((size_t)(y0 * 16 + x1)) * 32 + f];
        float v10 = a32[((size_t)(y1 * 16 + x0)) * 32 + f];
        float v11 = a32[((size_t)(y1 * 16 + x1)) * 32 + f];
        float vv = (1.f - fy) * ((1.f - fx) * v00 + fx * v01)
                 + fy * ((1.f - fx) * v10 + fx * v11);
        cat[(size_t)p * 96 + 64 + f] = f2bf(vv);
    }
}

// ---------- pack 3x3 fuse weights to MFMA B-fragment order ----------
// wfp[(((tap*3+kt)*6+nt)*64+l)*8+j] = wf[tap][k][n], k=kt*32+(l>>4)*8+j, n=nt*16+(l&15)
__global__ __launch_bounds__(256) void k_packf(
    const float* __restrict__ wf, short* __restrict__ wfp) {
    int i = blockIdx.x * 256 + threadIdx.x;   // 0..82943
    if (i >= 82944) return;
    int j = i & 7;
    int l = (i >> 3) & 63;
    int rest = i >> 9;       // 0..161
    int nt = rest % 6;
    int tk = rest / 6;       // 0..26
    int kt = tk % 3, tap = tk / 3;
    int k = kt * 32 + ((l >> 4) << 3) + j;
    int n = nt * 16 + (l & 15);
    wfp[i] = (short)f2bf(wf[((size_t)(tap * 96 + k)) * 96 + n]);
}

// ---------- 3x3 conv via bf16 MFMA implicit GEMM + BN + ReLU -> bf16 ----------
// 512 blocks, tile 8x16 px (128 rows), 4 waves: wave w -> pixel rows py=2w,2w+1.
// LDS: 10x18 px region, 256B/row pitch, chunk-XOR swizzle.
__global__ __launch_bounds__(256) void k_fuse2(
    const unsigned short* __restrict__ catb, const short* __restrict__ wfp,
    const float* __restrict__ sf, const float* __restrict__ bfb,
    unsigned short* __restrict__ featb) {
    __shared__ char Xb[180 * 256];
    int t = threadIdx.x;
    int by = (blockIdx.x >> 4) * 8;
    int bx = (blockIdx.x & 15) * 16;

    // stage region (chunks 0..11 = 96ch), zero-pad chunks 12..15
    for (int i = t; i < 2160; i += 256) {
        int rp = i / 12, cc = i % 12;
        int gy = by + rp / 18 - 1;
        int gx = bx + rp % 18 - 1;
        short8v v = {0, 0, 0, 0, 0, 0, 0, 0};
        if (gy >= 0 && gy < 256 && gx >= 0 && gx < 256)
            v = *(const short8v*)(catb + (size_t)(gy * 256 + gx) * 96 + cc * 8);
        *(short8v*)(Xb + rp * 256 + ((cc * 16) ^ ((rp & 7) << 4))) = v;
    }
    for (int i = t; i < 720; i += 256) {
        int rp = i >> 2, cc = 12 + (i & 3);
        short8v z = {0, 0, 0, 0, 0, 0, 0, 0};
        *(short8v*)(Xb + rp * 256 + ((cc * 16) ^ ((rp & 7) << 4))) = z;
    }
    __syncthreads();

    int lane = t & 63, wid = t >> 6;
    int px = lane & 15, kb = (lane >> 4) * 16;

    float4v acc[2][6];
#pragma unroll
    for (int rt = 0; rt < 2; ++rt)
#pragma unroll
        for (int nt = 0; nt < 6; ++nt)
            acc[rt][nt] = (float4v){0.f, 0.f, 0.f, 0.f};

#pragma unroll
    for (int ky = 0; ky < 3; ++ky) {
#pragma unroll
        for (int kx = 0; kx < 3; ++kx) {
#pragma unroll
            for (int kt = 0; kt < 3; ++kt) {
                int rp0 = (2 * wid + ky) * 18 + px + kx;
                int rp1 = rp0 + 18;
                short8v a0 = *(short8v*)(Xb + rp0 * 256 + ((kt * 64 + kb) ^ ((rp0 & 7) << 4)));
                short8v a1 = *(short8v*)(Xb + rp1 * 256 + ((kt * 64 + kb) ^ ((rp1 & 7) << 4)));
                const short8v* bp = (const short8v*)wfp
                    + (size_t)(((ky * 3 + kx) * 3 + kt) * 6) * 64 + lane;
#pragma unroll
                for (int nt = 0; nt < 6; ++nt) {
                    short8v b = bp[nt * 64];
                    acc[0][nt] = __builtin_amdgcn_mfma_f32_16x16x32_bf16(a0, b, acc[0][nt], 0, 0, 0);
                    acc[1][nt] = __builtin_amdgcn_mfma_f32_16x16x32_bf16(a1, b, acc[1][nt], 0, 0, 0);
                }
            }
        }
    }

    int col = lane & 15, rbase = (lane >> 4) * 4;
#pragma unroll
    for (int rt = 0; rt < 2; ++rt) {
        int gy = by + 2 * wid + rt;
#pragma unroll
        for (int nt = 0; nt < 6; ++nt) {
            int ch = nt * 16 + col;
            float sc = sf[ch], bi = bfb[ch];
#pragma unroll
            for (int j = 0; j < 4; ++j) {
                int gx = bx + rbase + j;
                float v = fmaxf(fmaf(acc[rt][nt][j], sc, bi), 0.f);
                featb[(size_t)(gy * 256 + gx) * 96 + ch] = f2bf(v);
            }
        }
    }
}

// ---------- pack MLP weights into MFMA B-fragment order (bf16) ----------
__global__ __launch_bounds__(256) void k_pack(
    const float* __restrict__ w0, const float* __restrict__ w1,
    short* __restrict__ w0p, short* __restrict__ w1p) {
    int i = blockIdx.x * 256 + threadIdx.x;   // 0..16383
    int j = i & 7;
    int l = (i >> 3) & 63;
    int nt = (i >> 9) & 7;
    int kt = i >> 12;
    int k = kt * 32 + ((l >> 4) << 3) + j;
    int n = nt * 16 + (l & 15);
    w0p[i] = (k < 98) ? (short)f2bf(w0[k * 128 + n]) : (short)0;
    w1p[i] = (short)f2bf(w1[k * 128 + n]);
}

// ---------- fused LIIF query + MLP (bf16 MFMA) + ensemble ----------
__global__ __launch_bounds__(256) void k_mlp2(
    const unsigned short* __restrict__ featb,
    const short* __restrict__ w0p, const float* __restrict__ b0g,
    const short* __restrict__ w1p, const float* __restrict__ b1g,
    const float* __restrict__ w2g, const float* __restrict__ b2g,
    float* __restrict__ out) {
    __shared__ short8v Xs[128 * 128 / 8];   // 32KB bf16 [row][k], XOR-swizzled
    __shared__ float areas[128];
    __shared__ float preds[128];
    char* Xb = (char*)Xs;
    int t = threadIdx.x;

    // ---- phase 0: gather X = [feat(96) | ry rx | 0-pad] (bf16 copy) ----
    {
        int row = t >> 1, hf = t & 1;
        int pixl = row >> 2, br = row & 3;
        int p = blockIdx.x * 32 + pixl;
        int qy = p >> 9, qx = p & 511;
        float vx = (br & 2) ? 1.f : -1.f;
        float vy = (br & 1) ? 1.f : -1.f;
        float gy = (qy + 0.5f) * (1.f / 256.f) - 1.f;
        float gx = (qx + 0.5f) * (1.f / 256.f) - 1.f;
        float csy = fminf(fmaxf(gy + (vx * (1.f / 256.f) + 1e-6f), -1.f + 1e-6f), 1.f - 1e-6f);
        float csx = fminf(fmaxf(gx + (vy * (1.f / 256.f) + 1e-6f), -1.f + 1e-6f), 1.f - 1e-6f);
        int iy = min(max((int)rintf((csy + 1.f) * 128.f - 0.5f), 0), 255);
        int ix = min(max((int)rintf((csx + 1.f) * 128.f - 0.5f), 0), 255);
        float qcy = (iy + 0.5f) * (1.f / 128.f) - 1.f;
        float qcx = (ix + 0.5f) * (1.f / 128.f) - 1.f;
        float ry = (gy - qcy) * 256.f;
        float rx = (gx - qcx) * 256.f;
        const unsigned short* fp = featb + (size_t)(iy * 256 + ix) * 96;
        int rswz = (row & 7) << 4;
        if (hf == 0) {
#pragma unroll
            for (int cc = 0; cc < 8; ++cc) {
                short8v v = *(const short8v*)(fp + cc * 8);
                *(short8v*)(Xb + row * 256 + ((cc * 16) ^ rswz)) = v;
            }
        } else {
#pragma unroll
            for (int cc = 8; cc < 12; ++cc) {
                short8v v = *(const short8v*)(fp + cc * 8);
                *(short8v*)(Xb + row * 256 + ((cc * 16) ^ rswz)) = v;
            }
            short8v vc = {0, 0, 0, 0, 0, 0, 0, 0};
            vc[0] = (short)f2bf(ry); vc[1] = (short)f2bf(rx);
            *(short8v*)(Xb + row * 256 + ((12 * 16) ^ rswz)) = vc;
            short8v z = {0, 0, 0, 0, 0, 0, 0, 0};
#pragma unroll
            for (int cc = 13; cc < 16; ++cc)
                *(short8v*)(Xb + row * 256 + ((cc * 16) ^ rswz)) = z;
            areas[row] = fabsf(ry * rx) + 1e-9f;
        }
    }
    __syncthreads();

    int lane = t & 63, wid = t >> 6;
    int arow0 = wid * 32 + (lane & 15);
    int arow1 = arow0 + 16;
    int kb = (lane >> 4) * 16;
    int rs0 = (arow0 & 7) << 4;
    int col = lane & 15;
    int rbase = (lane >> 4) * 4;

    float4v acc[2][8];
#pragma unroll
    for (int rt = 0; rt < 2; ++rt)
#pragma unroll
        for (int nt = 0; nt < 8; ++nt)
            acc[rt][nt] = (float4v){0.f, 0.f, 0.f, 0.f};

    // ---- layer 0 ----
#pragma unroll
    for (int kt = 0; kt < 4; ++kt) {
        short8v a0 = *(short8v*)(Xb + arow0 * 256 + ((kt * 64 + kb) ^ rs0));
        short8v a1 = *(short8v*)(Xb + arow1 * 256 + ((kt * 64 + kb) ^ rs0));
        const short8v* bp = (const short8v*)w0p + kt * 512 + lane;
#pragma unroll
        for (int nt = 0; nt < 8; ++nt) {
            short8v b = bp[nt * 64];
            acc[0][nt] = __builtin_amdgcn_mfma_f32_16x16x32_bf16(a0, b, acc[0][nt], 0, 0, 0);
            acc[1][nt] = __builtin_amdgcn_mfma_f32_16x16x32_bf16(a1, b, acc[1][nt], 0, 0, 0);
        }
    }
    __syncthreads();

    // bias + relu, write H (bf16) into same LDS
#pragma unroll
    for (int rt = 0; rt < 2; ++rt) {
#pragma unroll
        for (int nt = 0; nt < 8; ++nt) {
            float b0v = b0g[nt * 16 + col];
#pragma unroll
            for (int j = 0; j < 4; ++j) {
                int rr = wid * 32 + rt * 16 + rbase + j;
                float h = fmaxf(acc[rt][nt][j] + b0v, 0.f);
                int byteoff = rr * 256 + (((nt * 32 + col * 2)) ^ ((rr & 7) << 4));
                *(short*)(Xb + byteoff) = (short)f2bf(h);
            }
        }
    }
    __syncthreads();

#pragma unroll
    for (int rt = 0; rt < 2; ++rt)
#pragma unroll
        for (int nt = 0; nt < 8; ++nt)
            acc[rt][nt] = (float4v){0.f, 0.f, 0.f, 0.f};

    // ---- layer 1 ----
#pragma unroll
    for (int kt = 0; kt < 4; ++kt) {
        short8v a0 = *(short8v*)(Xb + arow0 * 256 + ((kt * 64 + kb) ^ rs0));
        short8v a1 = *(short8v*)(Xb + arow1 * 256 + ((kt * 64 + kb) ^ rs0));
        const short8v* bp = (const short8v*)w1p + kt * 512 + lane;
#pragma unroll
        for (int nt = 0; nt < 8; ++nt) {
            short8v b = bp[nt * 64];
            acc[0][nt] = __builtin_amdgcn_mfma_f32_16x16x32_bf16(a0, b, acc[0][nt], 0, 0, 0);
            acc[1][nt] = __builtin_amdgcn_mfma_f32_16x16x32_bf16(a1, b, acc[1][nt], 0, 0, 0);
        }
    }

    // ---- fused layer 2 + reduction ----
    float b1v[8], w2v[8];
#pragma unroll
    for (int nt = 0; nt < 8; ++nt) {
        b1v[nt] = b1g[nt * 16 + col];
        w2v[nt] = w2g[nt * 16 + col];
    }
    float part[2][4];
#pragma unroll
    for (int rt = 0; rt < 2; ++rt)
#pragma unroll
        for (int j = 0; j < 4; ++j) part[rt][j] = 0.f;
#pragma unroll
    for (int rt = 0; rt < 2; ++rt)
#pragma unroll
        for (int nt = 0; nt < 8; ++nt)
#pragma unroll
            for (int j = 0; j < 4; ++j)
                part[rt][j] += fmaxf(acc[rt][nt][j] + b1v[nt], 0.f) * w2v[nt];
#pragma unroll
    for (int off = 8; off >= 1; off >>= 1)
#pragma unroll
        for (int rt = 0; rt < 2; ++rt)
#pragma unroll
            for (int j = 0; j < 4; ++j)
                part[rt][j] += __shfl_xor(part[rt][j], off);
    if ((lane & 15) == 0) {
        float bb = b2g[0];
#pragma unroll
        for (int rt = 0; rt < 2; ++rt)
#pragma unroll
            for (int j = 0; j < 4; ++j)
                preds[wid * 32 + rt * 16 + rbase + j] = part[rt][j] + bb;
    }
    __syncthreads();

    if (t < 32) {
        int p = blockIdx.x * 32 + t;
        float p0 = preds[t * 4 + 0], p1 = preds[t * 4 + 1];
        float p2 = preds[t * 4 + 2], p3 = preds[t * 4 + 3];
        float a0 = areas[t * 4 + 0], A1 = areas[t * 4 + 1];
        float A2 = areas[t * 4 + 2], A3 = areas[t * 4 + 3];
        out[p] = (p0 * A3 + p1 * A2 + p2 * A1 + p3 * a0) / (a0 + A1 + A2 + A3);
    }
}

// ---------- host launcher ----------
extern "C" void kernel_launch(void* const* d_in, const int* in_sizes, int n_in,
                              void* d_out, int out_size, void* d_ws, size_t ws_size,
                              hipStream_t stream) {
    const float* feats2 = (const float*)d_in[0];
    const float* feats4 = (const float*)d_in[1];
    const float* feats32 = (const float*)d_in[2];
    const float* w2 = (const float*)d_in[4];
    const float* s2 = (const float*)d_in[5];
    const float* b2 = (const float*)d_in[6];
    const float* w4 = (const float*)d_in[7];
    const float* s4 = (const float*)d_in[8];
    const float* b4 = (const float*)d_in[9];
    const float* w32 = (const float*)d_in[10];
    const float* s32 = (const float*)d_in[11];
    const float* b32 = (const float*)d_in[12];
    const float* wf = (const float*)d_in[13];
    const float* sf = (const float*)d_in[14];
    const float* bf = (const float*)d_in[15];
    const float* mw0 = (const float*)d_in[16];
    const float* mb0 = (const float*)d_in[17];
    const float* mw1 = (const float*)d_in[18];
    const float* mb1 = (const float*)d_in[19];
    const float* mw2 = (const float*)d_in[20];
    const float* mb2 = (const float*)d_in[21];

    float* a4buf = (float*)d_ws;                          // 128*128*32 f32
    float* a32buf = a4buf + 524288;                       // 16*16*32 f32
    unsigned short* catb16 = (unsigned short*)(a32buf + 8192);   // 65536*96 bf16
    unsigned short* featb16 = catb16 + 6291456;                  // 65536*96 bf16
    short* w0p = (short*)(featb16 + 6291456);             // 16384 bf16
    short* w1p = w0p + 16384;
    short* wfp = w1p + 16384;                             // 82944 bf16

    k_pack<<<64, 256, 0, stream>>>(mw0, mw1, w0p, w1p);
    k_packf<<<324, 256, 0, stream>>>(wf, wfp);
    k_branch<128><<<2048, 256, 0, stream>>>(feats4, w4, s4, b4, a4buf, 16384);
    k_branch<256><<<32, 256, 0, stream>>>(feats32, w32, s32, b32, a32buf, 256);
    k_cat<<<8192, 256, 0, stream>>>(feats2, w2, s2, b2, a4buf, a32buf, catb16);
    k_fuse2<<<512, 256, 0, stream>>>(catb16, wfp, sf, bf, featb16);
    k_mlp2<<<8192, 256, 0, stream>>>(featb16, w0p, mb0, w1p, mb1, mw2, mb2,
                                     (float*)d_out);
}